// Round 1
// baseline (1037.778 us; speedup 1.0000x reference)
//
#include <hip/hip_runtime.h>
#include <math.h>

#define N_NODES 50000
#define N_EDGES 800000
#define E_TOT   (N_EDGES + N_NODES)   /* 850000: edges + self loops */
#define HEADS   4
#define CH      128                   /* per-head channels, both layers */
#define NOUT    512                   /* HEADS*CH, GEMM output width, both layers */
#define NEG_SLOPE 0.2f

// ---------------- CSR build ----------------

__global__ __launch_bounds__(256) void count_deg(const int* __restrict__ ei,
                                                 int* __restrict__ deg) {
  int e = blockIdx.x * 256 + threadIdx.x;
  if (e >= E_TOT) return;
  int dst = (e < N_EDGES) ? ei[N_EDGES + e] : (e - N_EDGES);
  atomicAdd(&deg[dst], 1);
}

__global__ __launch_bounds__(1024) void scan_deg(const int* __restrict__ deg,
                                                 int* __restrict__ row_ptr) {
  __shared__ int sdata[1024];
  int tid = threadIdx.x;
  int base = 0;
  for (int start = 0; start < N_NODES; start += 1024) {
    int i = start + tid;
    int v = (i < N_NODES) ? deg[i] : 0;
    sdata[tid] = v;
    __syncthreads();
    for (int off = 1; off < 1024; off <<= 1) {
      int t = (tid >= off) ? sdata[tid - off] : 0;
      __syncthreads();
      if (tid >= off) sdata[tid] += t;
      __syncthreads();
    }
    if (i < N_NODES) row_ptr[i + 1] = base + sdata[tid];
    base += sdata[1023];
    __syncthreads();
  }
  if (tid == 0) row_ptr[0] = 0;
}

__global__ __launch_bounds__(256) void scatter_edges(const int* __restrict__ ei,
                                                     const int* __restrict__ row_ptr,
                                                     int* __restrict__ cursor,
                                                     int* __restrict__ col) {
  int e = blockIdx.x * 256 + threadIdx.x;
  if (e >= E_TOT) return;
  int src, dst;
  if (e < N_EDGES) { src = ei[e]; dst = ei[N_EDGES + e]; }
  else             { src = e - N_EDGES; dst = src; }
  int pos = atomicAdd(&cursor[dst], 1);
  col[row_ptr[dst] + pos] = src;
}

// ---------------- fp32 GEMM: C[M,512] = A[M,K] @ W[512,K]^T ----------------
// BM=BN=128, BK=16, 256 threads, 8x8 per thread.

__global__ __launch_bounds__(256) void gemm_awt(const float* __restrict__ A,
                                                const float* __restrict__ W,
                                                float* __restrict__ C,
                                                int M, int K) {
  __shared__ float As[16][132];
  __shared__ float Bs[16][132];
  const int tid = threadIdx.x;
  const int tx = tid & 15;        // 0..15 -> n sub-tile
  const int ty = tid >> 4;        // 0..15 -> m sub-tile
  const int m0 = blockIdx.x * 128;
  const int n0 = blockIdx.y * 128;

  float acc[8][8];
#pragma unroll
  for (int i = 0; i < 8; i++)
#pragma unroll
    for (int j = 0; j < 8; j++) acc[i][j] = 0.f;

  const int lr = tid >> 1;        // 0..127 row within tile
  const int lq = (tid & 1) * 8;   // 0 or 8 (k offset)
  const bool avalid = (m0 + lr) < M;
  const float* Ap = A + (size_t)(m0 + lr) * K + lq;
  const float* Wp = W + (size_t)(n0 + lr) * K + lq;

  for (int k0 = 0; k0 < K; k0 += 16) {
    float4 a0 = make_float4(0.f, 0.f, 0.f, 0.f), a1 = a0;
    if (avalid) {
      a0 = *(const float4*)(Ap + k0);
      a1 = *(const float4*)(Ap + k0 + 4);
    }
    float4 b0 = *(const float4*)(Wp + k0);
    float4 b1 = *(const float4*)(Wp + k0 + 4);
    __syncthreads();
    As[lq + 0][lr] = a0.x; As[lq + 1][lr] = a0.y;
    As[lq + 2][lr] = a0.z; As[lq + 3][lr] = a0.w;
    As[lq + 4][lr] = a1.x; As[lq + 5][lr] = a1.y;
    As[lq + 6][lr] = a1.z; As[lq + 7][lr] = a1.w;
    Bs[lq + 0][lr] = b0.x; Bs[lq + 1][lr] = b0.y;
    Bs[lq + 2][lr] = b0.z; Bs[lq + 3][lr] = b0.w;
    Bs[lq + 4][lr] = b1.x; Bs[lq + 5][lr] = b1.y;
    Bs[lq + 6][lr] = b1.z; Bs[lq + 7][lr] = b1.w;
    __syncthreads();
#pragma unroll
    for (int kk = 0; kk < 16; kk++) {
      float4 av0 = *(const float4*)&As[kk][ty * 8];
      float4 av1 = *(const float4*)&As[kk][ty * 8 + 4];
      float4 bv0 = *(const float4*)&Bs[kk][tx * 8];
      float4 bv1 = *(const float4*)&Bs[kk][tx * 8 + 4];
      float a[8] = {av0.x, av0.y, av0.z, av0.w, av1.x, av1.y, av1.z, av1.w};
      float b[8] = {bv0.x, bv0.y, bv0.z, bv0.w, bv1.x, bv1.y, bv1.z, bv1.w};
#pragma unroll
      for (int i = 0; i < 8; i++)
#pragma unroll
        for (int j = 0; j < 8; j++) acc[i][j] = fmaf(a[i], b[j], acc[i][j]);
    }
  }

#pragma unroll
  for (int i = 0; i < 8; i++) {
    int m = m0 + ty * 8 + i;
    if (m < M) {
      float4 s0 = make_float4(acc[i][0], acc[i][1], acc[i][2], acc[i][3]);
      float4 s1 = make_float4(acc[i][4], acc[i][5], acc[i][6], acc[i][7]);
      *(float4*)&C[(size_t)m * NOUT + n0 + tx * 8]     = s0;
      *(float4*)&C[(size_t)m * NOUT + n0 + tx * 8 + 4] = s1;
    }
  }
}

// ---------------- per-node attention scalars: a_s[n,h], a_d[n,h] ----------------
// one wave per node; lane -> (h = lane>>4, 8 channels at (lane&15)*8)

__global__ __launch_bounds__(256) void node_att(const float* __restrict__ xh,
                                                const float* __restrict__ att_s,
                                                const float* __restrict__ att_d,
                                                float* __restrict__ as_,
                                                float* __restrict__ ad_) {
  int node = (blockIdx.x * 256 + threadIdx.x) >> 6;
  if (node >= N_NODES) return;
  int lane = threadIdx.x & 63;
  int h = lane >> 4, ls = lane & 15, cb = ls * 8;
  const float4* xp = (const float4*)(xh + (size_t)node * NOUT + h * CH + cb);
  const float4* sp = (const float4*)(att_s + h * CH + cb);
  const float4* dp = (const float4*)(att_d + h * CH + cb);
  float4 v0 = xp[0], v1 = xp[1];
  float4 s0 = sp[0], s1 = sp[1];
  float4 d0 = dp[0], d1 = dp[1];
  float ps = v0.x * s0.x + v0.y * s0.y + v0.z * s0.z + v0.w * s0.w +
             v1.x * s1.x + v1.y * s1.y + v1.z * s1.z + v1.w * s1.w;
  float pd = v0.x * d0.x + v0.y * d0.y + v0.z * d0.z + v0.w * d0.w +
             v1.x * d1.x + v1.y * d1.y + v1.z * d1.z + v1.w * d1.w;
#pragma unroll
  for (int m = 1; m < 16; m <<= 1) {
    ps += __shfl_xor(ps, m, 64);
    pd += __shfl_xor(pd, m, 64);
  }
  if (ls == 0) {
    as_[node * HEADS + h] = ps;
    ad_[node * HEADS + h] = pd;
  }
}

// ---------------- GAT aggregation (softmax over incoming edges, head mean) ----------------
// one wave per dst node. lane -> (h, 8 channels). Two passes: max, then exp/accum.

__global__ __launch_bounds__(256) void gat_aggregate(const float* __restrict__ xh,
                                                     const float* __restrict__ as_,
                                                     const float* __restrict__ ad_,
                                                     const int* __restrict__ row_ptr,
                                                     const int* __restrict__ col,
                                                     const float* __restrict__ bias,
                                                     float* __restrict__ out) {
  int node = (blockIdx.x * 256 + threadIdx.x) >> 6;
  if (node >= N_NODES) return;
  int lane = threadIdx.x & 63;
  int h = lane >> 4, ls = lane & 15, cb = ls * 8;
  int s = row_ptr[node], e = row_ptr[node + 1];
  float adh = ad_[node * HEADS + h];

  // pass 1: segment max of leaky(alpha), strided over 16 lanes per head group
  float m = -INFINITY;
  for (int i = s + ls; i < e; i += 16) {
    int src = col[i];
    float a = as_[src * HEADS + h] + adh;
    a = (a >= 0.f) ? a : NEG_SLOPE * a;
    m = fmaxf(m, a);
  }
#pragma unroll
  for (int mask = 1; mask < 16; mask <<= 1) m = fmaxf(m, __shfl_xor(m, mask, 64));

  // pass 2: wave-serial over edges; all 64 lanes gather one 2KB xh row per edge
  float acc[8];
#pragma unroll
  for (int j = 0; j < 8; j++) acc[j] = 0.f;
  float denom = 0.f;
  for (int i = s; i < e; ++i) {
    int src = col[i];
    float a = as_[src * HEADS + h] + adh;
    a = (a >= 0.f) ? a : NEG_SLOPE * a;
    float w = __expf(a - m);
    denom += w;
    const float4* p = (const float4*)(xh + (size_t)src * NOUT + h * CH + cb);
    float4 v0 = p[0], v1 = p[1];
    acc[0] = fmaf(w, v0.x, acc[0]); acc[1] = fmaf(w, v0.y, acc[1]);
    acc[2] = fmaf(w, v0.z, acc[2]); acc[3] = fmaf(w, v0.w, acc[3]);
    acc[4] = fmaf(w, v1.x, acc[4]); acc[5] = fmaf(w, v1.y, acc[5]);
    acc[6] = fmaf(w, v1.z, acc[6]); acc[7] = fmaf(w, v1.w, acc[7]);
  }
  float inv = 1.f / (denom + 1e-16f);
#pragma unroll
  for (int j = 0; j < 8; j++) acc[j] *= inv;

  // mean over heads: butterfly over lane bits 4,5
#pragma unroll
  for (int j = 0; j < 8; j++) {
    acc[j] += __shfl_xor(acc[j], 16, 64);
    acc[j] += __shfl_xor(acc[j], 32, 64);
  }
  if (h == 0) {
    float4 o0, o1;
    o0.x = acc[0] * 0.25f + bias[cb + 0];
    o0.y = acc[1] * 0.25f + bias[cb + 1];
    o0.z = acc[2] * 0.25f + bias[cb + 2];
    o0.w = acc[3] * 0.25f + bias[cb + 3];
    o1.x = acc[4] * 0.25f + bias[cb + 4];
    o1.y = acc[5] * 0.25f + bias[cb + 5];
    o1.z = acc[6] * 0.25f + bias[cb + 6];
    o1.w = acc[7] * 0.25f + bias[cb + 7];
    *(float4*)&out[(size_t)node * CH + cb]     = o0;
    *(float4*)&out[(size_t)node * CH + cb + 4] = o1;
  }
}

// ---------------- launch ----------------

extern "C" void kernel_launch(void* const* d_in, const int* in_sizes, int n_in,
                              void* d_out, int out_size, void* d_ws, size_t ws_size,
                              hipStream_t stream) {
  const float* x      = (const float*)d_in[0];
  const int*   ei     = (const int*)  d_in[1];
  const float* W1     = (const float*)d_in[2];
  const float* att_s1 = (const float*)d_in[3];
  const float* att_d1 = (const float*)d_in[4];
  const float* b1     = (const float*)d_in[5];
  const float* W2     = (const float*)d_in[6];
  const float* att_s2 = (const float*)d_in[7];
  const float* att_d2 = (const float*)d_in[8];
  const float* b2     = (const float*)d_in[9];
  float* out = (float*)d_out;

  char* ws = (char*)d_ws;
  size_t off = 0;
  auto alloc = [&](size_t bytes) -> void* {
    void* p = ws + off;
    off += (bytes + 255) & ~(size_t)255;
    return p;
  };
  float* xh      = (float*)alloc((size_t)N_NODES * NOUT * 4);  // 102.4 MB, reused by both layers
  float* hbuf    = (float*)alloc((size_t)N_NODES * CH * 4);    // 25.6 MB (layer-1 output)
  float* as_     = (float*)alloc((size_t)N_NODES * HEADS * 4);
  float* ad_     = (float*)alloc((size_t)N_NODES * HEADS * 4);
  int*   row_ptr = (int*)alloc((size_t)(N_NODES + 1) * 4);
  int*   cursor  = (int*)alloc((size_t)N_NODES * 4);
  int*   col     = (int*)alloc((size_t)E_TOT * 4);

  const int edge_blocks = (E_TOT + 255) / 256;
  const int node_wave_blocks = (N_NODES + 3) / 4;  // 4 waves (nodes) per 256-thread block

  // CSR build (by dst)
  hipMemsetAsync(cursor, 0, (size_t)N_NODES * 4, stream);
  count_deg<<<edge_blocks, 256, 0, stream>>>(ei, cursor);
  scan_deg<<<1, 1024, 0, stream>>>(cursor, row_ptr);
  hipMemsetAsync(cursor, 0, (size_t)N_NODES * 4, stream);
  scatter_edges<<<edge_blocks, 256, 0, stream>>>(ei, row_ptr, cursor, col);

  dim3 ggrid((N_NODES + 127) / 128, NOUT / 128);

  // layer 1
  gemm_awt<<<ggrid, 256, 0, stream>>>(x, W1, xh, N_NODES, 256);
  node_att<<<node_wave_blocks, 256, 0, stream>>>(xh, att_s1, att_d1, as_, ad_);
  gat_aggregate<<<node_wave_blocks, 256, 0, stream>>>(xh, as_, ad_, row_ptr, col, b1, hbuf);

  // layer 2
  gemm_awt<<<ggrid, 256, 0, stream>>>(hbuf, W2, xh, N_NODES, 128);
  node_att<<<node_wave_blocks, 256, 0, stream>>>(xh, att_s2, att_d2, as_, ad_);
  gat_aggregate<<<node_wave_blocks, 256, 0, stream>>>(xh, as_, ad_, row_ptr, col, b2, out);
}